// Round 13
// baseline (169.371 us; speedup 1.0000x reference)
//
#include <hip/hip_runtime.h>

// Problem constants (fixed by the reference)
#define N_NODES 20000
#define N_EDGES 320000
#define ETOT    (N_EDGES + N_NODES)   // edges + self-loops = 340000
#define HEADS   10
#define F_IN    32
#define C1      (HEADS * F_IN)        // 320
#define C2      128
#define NB      100
#define PER     200
#define CAP     96                    // CSR bucket capacity (max in-degree << 96)
#define HSTRIDE 328                   // padded tile row stride (ushort) -> 656B, 16B-aligned
#define X2STRIDE 136                  // padded x2-tile row stride (f16) -> 272B, 16B-aligned

typedef __attribute__((ext_vector_type(8))) short bf16x8;   // MFMA A/B frag (4 VGPRs)
typedef __attribute__((ext_vector_type(4))) float floatx4;  // MFMA C/D frag
typedef _Float16 f16;
typedef _Float16 f16x2 __attribute__((ext_vector_type(2)));
typedef _Float16 f16x8 __attribute__((ext_vector_type(8)));

static __device__ __forceinline__ unsigned short f2bf(float f) {
    unsigned int u = __float_as_uint(f);
    unsigned int r = (u + 0x7fffu + ((u >> 16) & 1u)) >> 16;   // RNE
    return (unsigned short)r;
}

// ---------------------------------------------------------------------------
// Combined prep: cursor+pooled zero + W2/W1/FC MFMA B-frag prep + WA fold
// + feats->f16
// ---------------------------------------------------------------------------
#define CURZ_BLOCKS ((N_NODES + 255) / 256)             // 79
#define PLZ_BLOCKS  ((NB * C2 + 255) / 256)             // 50
#define W2P_BLOCKS  ((C1 * C2 + 255) / 256)             // 160
#define W1P_BLOCKS  ((HEADS * F_IN * F_IN + 255) / 256) // 40
#define FCP_BLOCKS  ((C2 * C2 + 255) / 256)             // 64
#define F16_BLOCKS  ((N_NODES * F_IN / 4 + 255) / 256)  // 625 (x4 vectorized)
__global__ void prep_kernel(int* __restrict__ cursor, int* __restrict__ pooledi,
                            const float* __restrict__ W2, unsigned short* __restrict__ W2p,
                            const float* __restrict__ W1, unsigned short* __restrict__ W1p,
                            const float* __restrict__ fcw, f16* __restrict__ FCp,
                            const float* __restrict__ a1s, const float* __restrict__ a1d,
                            float* __restrict__ WAs, float* __restrict__ WAd,
                            const float* __restrict__ feats, f16* __restrict__ feats16) {
    unsigned int b = blockIdx.x;
    if (b < CURZ_BLOCKS) {
        int o = b * 256 + threadIdx.x;
        if (o < N_NODES) cursor[o] = 0;
        return;
    }
    b -= CURZ_BLOCKS;
    if (b < PLZ_BLOCKS) {
        int o = b * 256 + threadIdx.x;
        if (o < NB * C2) pooledi[o] = 0;   // 0.0f bits; x2 >= 0 so identity for max
        return;
    }
    b -= PLZ_BLOCKS;
    if (b < W2P_BLOCKS) {
        int o = b * 256 + threadIdx.x;   // 40960
        if (o >= C1 * C2) return;
        int j    = o & 7;
        int lane = (o >> 3) & 63;
        int ct   = (o >> 9) & 7;
        int kb   = o >> 12;
        int k = kb * 32 + (lane >> 4) * 8 + j;
        int n = ct * 16 + (lane & 15);
        W2p[o] = f2bf(W2[k * C2 + n]);
        return;
    }
    b -= W2P_BLOCKS;
    if (b < W1P_BLOCKS) {
        // B-frag for h1 GEMM: W1p[((h*2+ct)*64+lane)*8+j] = W1[quad*8+j][h*32+ct*16+col]
        int o = b * 256 + threadIdx.x;   // 10240
        if (o >= HEADS * F_IN * F_IN) return;
        int j    = o & 7;
        int lane = (o >> 3) & 63;
        int ct   = (o >> 9) & 1;
        int h    = o >> 10;
        int k = (lane >> 4) * 8 + j;
        int f = ct * 16 + (lane & 15);
        W1p[o] = f2bf(W1[k * C1 + h * 32 + f]);
        return;
    }
    b -= W1P_BLOCKS;
    if (b < FCP_BLOCKS) {
        // B-frag (f16) for fc GEMM, K=128: kb<4, ct<8
        int o = b * 256 + threadIdx.x;   // 16384
        if (o >= C2 * C2) return;
        int j    = o & 7;
        int lane = (o >> 3) & 63;
        int ct   = (o >> 9) & 7;
        int kb   = o >> 12;
        int k = kb * 32 + (lane >> 4) * 8 + j;
        int n = ct * 16 + (lane & 15);
        FCp[o] = (f16)fcw[k * C2 + n];
        return;
    }
    b -= FCP_BLOCKS;
    if (b < F16_BLOCKS) {
        int o = b * 256 + threadIdx.x;
        if (o < N_NODES * F_IN / 4) {
            float4 v = ((const float4*)feats)[o];
            f16* d = feats16 + 4 * o;
            d[0] = (f16)v.x; d[1] = (f16)v.y; d[2] = (f16)v.z; d[3] = (f16)v.w;
        }
        return;
    }
    // one block: fold attention vectors through W1 -> WAs/WAd [32][10]
    int t = threadIdx.x;
    for (int o = t; o < C1; o += 256) {
        int k = o & 31, h = o >> 5;
        float ss = 0.f, dd = 0.f;
#pragma unroll
        for (int f = 0; f < F_IN; f++) {
            float wv = W1[k * C1 + h * 32 + f];
            ss += wv * a1s[h * 32 + f];
            dd += wv * a1d[h * 32 + f];
        }
        WAs[k * HEADS + h] = ss;
        WAd[k * HEADS + h] = dd;
    }
}

// ---------------------------------------------------------------------------
// Fused: bucket-CSR scatter + layer-1 scores (independent work)
// ---------------------------------------------------------------------------
#define SCAT_BLOCKS ((ETOT + 255) / 256)
__global__ __launch_bounds__(256) void scatter_score_kernel(
        const int* __restrict__ ei, int* __restrict__ cursor, int* __restrict__ csr_src,
        const float* __restrict__ feats, const float* __restrict__ WAs,
        const float* __restrict__ WAd, float* __restrict__ s_src,
        float* __restrict__ s_dst) {
    if (blockIdx.x < SCAT_BLOCKS) {
        int e = blockIdx.x * 256 + threadIdx.x;
        if (e >= ETOT) return;
        int s, d;
        if (e < N_EDGES) { s = ei[e]; d = ei[N_EDGES + e]; }
        else             { s = e - N_EDGES; d = s; }
        int pos = atomicAdd(&cursor[d], 1);
        csr_src[(size_t)d * CAP + pos] = s;
        return;
    }
    __shared__ __align__(16) float A[64 * F_IN];   // 8 KB
    __shared__ float Ws[C1], Wd[C1];
    int t = threadIdx.x;
    int n0 = (blockIdx.x - SCAT_BLOCKS) * 64;
    int nrows = min(64, N_NODES - n0);
    if (nrows <= 0) return;
    for (int i = t; i < C1; i += 256) { Ws[i] = WAs[i]; Wd[i] = WAd[i]; }
    const float4* fs = (const float4*)(feats + (size_t)n0 * F_IN);
    float4* Af = (float4*)A;
    for (int i = t; i < nrows * 8; i += 256) Af[i] = fs[i];
    __syncthreads();
    for (int o = t; o < nrows * HEADS; o += 256) {
        int nl = o / HEADS, h = o - nl * HEADS;
        const float* ar = A + nl * F_IN;
        float ss = 0.f, dd = 0.f;
#pragma unroll
        for (int k = 0; k < F_IN; k++) {
            float av = ar[k];
            ss += av * Ws[k * HEADS + h];
            dd += av * Wd[k * HEADS + h];
        }
        s_src[(size_t)(n0 + nl) * HEADS + h] = ss;
        s_dst[(size_t)(n0 + nl) * HEADS + h] = dd;
    }
}

// ---------------------------------------------------------------------------
// Fused layer-1 gather + h1 + gemm2: block = one 16-node tile, 512 threads.
//   phase 0: wave w gathers nodes 16b+2w, +2w+1 (feats-gather, fdot2) ->
//            normalized gn tile (bf16) in padded LDS (no global round-trip)
//   phase 1: h1 = ELU(gn @ W1 + b1) per head (heads striped over 8 waves)
//   phase 2: xw2 = h1 @ W2 (f16 out, 1 col-tile/wave) + fused s2 scores
// ---------------------------------------------------------------------------
__global__ __launch_bounds__(512) void aggh1g2_kernel(
        const f16* __restrict__ feats16, const float* __restrict__ s_src,
        const float* __restrict__ s_dst, const int* __restrict__ deg_arr,
        const int* __restrict__ csr_src,
        const unsigned short* __restrict__ W1p, const float* __restrict__ b1,
        const unsigned short* __restrict__ W2p,
        const float* __restrict__ a_src, const float* __restrict__ a_dst,
        f16* __restrict__ xw2h, float* __restrict__ s_src2, float* __restrict__ s_dst2) {
    __shared__ __align__(4) f16 shP[8][HEADS * 64];      // 10 KB
    __shared__ __align__(8) int shS[8][64];              // 2 KB
    __shared__ __align__(16) unsigned short GT[16 * HSTRIDE];  // 10.25 KB
    __shared__ __align__(16) unsigned short H[16 * HSTRIDE];   // 10.25 KB
    __shared__ float redS[8][16], redD[8][16];           // 1 KB
    int w = threadIdx.x >> 6;            // 0..7
    int lane = threadIdx.x & 63;
    int k = lane & 31, half = lane >> 5;
    int row0 = blockIdx.x * 16;          // 1250 blocks
    f16* P = shP[w];
    int* S = shS[w];
    const f16x2 ones = {(f16)1.f, (f16)1.f};

    // ---- phase 0: gather, 2 nodes per wave ----
#pragma unroll
    for (int rep = 0; rep < 2; rep++) {
        int r = w * 2 + rep;
        int n = row0 + r;
        int beg = n * CAP, deg = deg_arr[n];
        const float* sdp = s_dst + (size_t)n * HEADS;
        float sd[10];
#pragma unroll
        for (int q = 0; q < 5; q++) {
            float2 v = *(const float2*)(sdp + 2 * q);
            sd[2 * q] = v.x; sd[2 * q + 1] = v.y;
        }
        float g[10], la[10];
#pragma unroll
        for (int h = 0; h < 10; h++) { g[h] = 0.f; la[h] = 0.f; }

        for (int c0 = 0; c0 < deg; c0 += 64) {
            int dc = min(deg - c0, 64);
            bool act = lane < dc;
            int s_e = csr_src[beg + c0 + min(lane, dc - 1)];
            const float* ssp = s_src + (size_t)s_e * HEADS;
            float p[10];
#pragma unroll
            for (int q = 0; q < 5; q++) {
                float2 v = *(const float2*)(ssp + 2 * q);
                float e0 = v.x + sd[2 * q];
                float e1 = v.y + sd[2 * q + 1];
                e0 = (e0 >= 0.f) ? e0 : 0.2f * e0;   // leaky_relu(0.2)
                e1 = (e1 >= 0.f) ? e1 : 0.2f * e1;
                p[2 * q]     = act ? __expf(e0) : 0.f;
                p[2 * q + 1] = act ? __expf(e1) : 0.f;
            }
            // stage transposed f16 weights; pad edges carry p = 0
            S[lane] = s_e;
#pragma unroll
            for (int h = 0; h < 10; h++) P[h * 64 + lane] = (f16)p[h];
            asm volatile("s_waitcnt lgkmcnt(0)" ::: "memory");

            int dcp = (dc + 3) & ~3;
            for (int i = 0; i < dcp; i += 4) {
                int e0 = i + half * 2;               // this half's edge pair
                int2 ss2 = *(const int2*)&S[e0];
                f16x2 v;
                v.x = feats16[(size_t)ss2.x * F_IN + k];
                v.y = feats16[(size_t)ss2.y * F_IN + k];
#pragma unroll
                for (int h = 0; h < 10; h++) {
                    f16x2 pp = *(const f16x2*)&P[h * 64 + e0];
                    g[h]  = __builtin_amdgcn_fdot2(pp, v, g[h], false);
                    la[h] = __builtin_amdgcn_fdot2(pp, ones, la[h], false);
                }
            }
            asm volatile("s_waitcnt lgkmcnt(0)" ::: "memory");  // reads done before next chunk
        }
#pragma unroll
        for (int h = 0; h < 10; h++) {
            g[h]  += __shfl_xor(g[h], 32);
            la[h] += __shfl_xor(la[h], 32);
        }
        if (half == 0) {
#pragma unroll
            for (int h = 0; h < 10; h++)
                GT[r * HSTRIDE + h * 32 + k] = f2bf(g[h] / fmaxf(la[h], 1e-16f));
        }
    }
    __syncthreads();

    // ---- phase 1: h1 per head, heads striped over waves ----
    int quad = lane >> 4, col = lane & 15;
    for (int h = w; h < 10; h += 8) {
        bf16x8 a = *(const bf16x8*)&GT[col * HSTRIDE + h * 32 + quad * 8];
        bf16x8 bA = ((const bf16x8*)W1p)[(h * 2 + 0) * 64 + lane];
        bf16x8 bB = ((const bf16x8*)W1p)[(h * 2 + 1) * 64 + lane];
        floatx4 z = {0.f, 0.f, 0.f, 0.f};
        floatx4 c0 = __builtin_amdgcn_mfma_f32_16x16x32_bf16(a, bA, z, 0, 0, 0);
        floatx4 c1 = __builtin_amdgcn_mfma_f32_16x16x32_bf16(a, bB, z, 0, 0, 0);
        float bias0 = b1[h * 32 + col];
        float bias1 = b1[h * 32 + 16 + col];
#pragma unroll
        for (int reg = 0; reg < 4; reg++) {
            int r = quad * 4 + reg;
            float o0 = c0[reg] + bias0;
            float o1 = c1[reg] + bias1;
            o0 = (o0 > 0.f) ? o0 : (__expf(o0) - 1.f);
            o1 = (o1 > 0.f) ? o1 : (__expf(o1) - 1.f);
            H[r * HSTRIDE + h * 32 + col]      = f2bf(o0);
            H[r * HSTRIDE + h * 32 + 16 + col] = f2bf(o1);
        }
    }
    __syncthreads();

    // ---- phase 2: gemm2, ct = w (16 cols per wave) ----
    floatx4 acc = {0.f, 0.f, 0.f, 0.f};
    const bf16x8* pb = (const bf16x8*)W2p;
#pragma unroll
    for (int kb = 0; kb < 10; kb++) {
        bf16x8 a = *(const bf16x8*)&H[(lane & 15) * HSTRIDE + kb * 32 + quad * 8];
        bf16x8 b = pb[(kb * 8 + w) * 64 + lane];
        acc = __builtin_amdgcn_mfma_f32_16x16x32_bf16(a, b, acc, 0, 0, 0);
    }
    float as = a_src[w * 16 + col], ad = a_dst[w * 16 + col];
#pragma unroll
    for (int reg = 0; reg < 4; reg++) {
        int row = row0 + quad * 4 + reg;
        float v = acc[reg];
        xw2h[(size_t)row * C2 + w * 16 + col] = (f16)v;
        float vs = v * as, vd = v * ad;
#pragma unroll
        for (int off = 8; off >= 1; off >>= 1) {
            vs += __shfl_xor(vs, off);
            vd += __shfl_xor(vd, off);
        }
        if (col == 0) { redS[w][quad * 4 + reg] = vs; redD[w][quad * 4 + reg] = vd; }
    }
    __syncthreads();
    if (threadIdx.x < 16) {
        float s = 0.f, d = 0.f;
#pragma unroll
        for (int ww = 0; ww < 8; ww++) { s += redS[ww][threadIdx.x]; d += redD[ww][threadIdx.x]; }
        s_src2[row0 + threadIdx.x] = s;
        s_dst2[row0 + threadIdx.x] = d;
    }
}

// ---------------------------------------------------------------------------
// Fused layer-2 aggregation + fc: block = one 16-node tile, 512 threads.
//   phase 1: wave w computes x2 (ReLU'd, f16) for nodes 16b+2w, +2w+1 into LDS
//   phase 2a: out = relu(X @ fc_w + fc_b) via f16 MFMA (1 col-tile/wave)
//   phase 2b: tile-local per-channel max -> atomicMax into pooled (f32 bits)
// ---------------------------------------------------------------------------
__global__ __launch_bounds__(512) void agg2fc_kernel(
        const f16* __restrict__ xw2h, const float* __restrict__ s_src2,
        const float* __restrict__ s_dst2, const int* __restrict__ deg_arr,
        const int* __restrict__ csr_src, const float* __restrict__ b2,
        const f16* __restrict__ FCp, const float* __restrict__ fcb,
        float* __restrict__ out, int* __restrict__ pooledi) {
    __shared__ __align__(8) int2 shE[8][64];          // 4 KB
    __shared__ __align__(16) f16 X[16 * X2STRIDE];    // 4.25 KB
    int w = threadIdx.x >> 6;
    int lane = threadIdx.x & 63;
    int row0 = blockIdx.x * 16;          // 1250 blocks
    int2* E = shE[w];

    // ---- phase 1: 2 nodes per wave ----
#pragma unroll
    for (int rep = 0; rep < 2; rep++) {
        int r = w * 2 + rep;
        int n = row0 + r;
        int beg = n * CAP, deg = deg_arr[n];
        float sd = s_dst2[n];
        float l = 0.f, a0 = 0.f, a1 = 0.f;

        for (int c0 = 0; c0 < deg; c0 += 64) {
            int dc = min(deg - c0, 64);
            bool act = lane < dc;
            int s_e = csr_src[beg + c0 + min(lane, dc - 1)];
            float e = s_src2[s_e] + sd;
            e = (e >= 0.f) ? e : 0.2f * e;
            float p = act ? __expf(e) : 0.f;
            float su = p;
#pragma unroll
            for (int off = 32; off >= 1; off >>= 1) su += __shfl_xor(su, off);
            l += su;

            E[lane] = make_int2(s_e, __float_as_int(p));
            asm volatile("s_waitcnt lgkmcnt(0)" ::: "memory");

            int dcr = (dc + 3) & ~3;                  // pad rows have p=0
            for (int i = 0; i < dcr; i += 4) {
                int2 e0 = E[i + 0], e1 = E[i + 1], e2 = E[i + 2], e3 = E[i + 3];
                f16x2 v0 = *(const f16x2*)(xw2h + (size_t)e0.x * C2 + 2 * lane);
                f16x2 v1 = *(const f16x2*)(xw2h + (size_t)e1.x * C2 + 2 * lane);
                f16x2 v2 = *(const f16x2*)(xw2h + (size_t)e2.x * C2 + 2 * lane);
                f16x2 v3 = *(const f16x2*)(xw2h + (size_t)e3.x * C2 + 2 * lane);
                float p0 = __int_as_float(e0.y), p1 = __int_as_float(e1.y);
                float p2 = __int_as_float(e2.y), p3 = __int_as_float(e3.y);
                a0 += p0 * (float)v0.x + p1 * (float)v1.x + p2 * (float)v2.x + p3 * (float)v3.x;
                a1 += p0 * (float)v0.y + p1 * (float)v1.y + p2 * (float)v2.y + p3 * (float)v3.y;
            }
            asm volatile("s_waitcnt lgkmcnt(0)" ::: "memory");
        }

        float linv = 1.f / fmaxf(l, 1e-16f);
        float2 bb = *(const float2*)(b2 + 2 * lane);
        f16x2 o;
        o.x = (f16)fmaxf(a0 * linv + bb.x, 0.f);
        o.y = (f16)fmaxf(a1 * linv + bb.y, 0.f);
        *(f16x2*)&X[r * X2STRIDE + 2 * lane] = o;
    }
    __syncthreads();

    // ---- phase 2a: fc MFMA — ct = w ----
    int quad = lane >> 4, col = lane & 15;
    floatx4 acc = {0.f, 0.f, 0.f, 0.f};
    const f16x8* pb = (const f16x8*)FCp;
#pragma unroll
    for (int kb = 0; kb < 4; kb++) {
        f16x8 a = *(const f16x8*)&X[(lane & 15) * X2STRIDE + kb * 32 + quad * 8];
        f16x8 b = pb[(kb * 8 + w) * 64 + lane];
        acc = __builtin_amdgcn_mfma_f32_16x16x32_f16(a, b, acc, 0, 0, 0);
    }
    float bias = fcb[w * 16 + col];
#pragma unroll
    for (int reg = 0; reg < 4; reg++) {
        int row = row0 + quad * 4 + reg;
        out[(size_t)row * C2 + w * 16 + col] = fmaxf(acc[reg] + bias, 0.f);
    }

    // ---- phase 2b: tile-local pooling max + atomicMax (threads 0..127) ----
    if (threadIdx.x < C2) {
        int c = threadIdx.x;
        int gA = row0 / PER;
        int gB = (row0 + 15) / PER;
        float mA = 0.f, mB = 0.f;        // x2 >= 0, 0 is identity
#pragma unroll
        for (int r = 0; r < 16; r++) {
            float v = (float)X[r * X2STRIDE + c];
            if ((row0 + r) / PER == gA) mA = fmaxf(mA, v);
            else                        mB = fmaxf(mB, v);
        }
        atomicMax(&pooledi[gA * C2 + c], __float_as_int(mA));
        if (gB != gA) atomicMax(&pooledi[gB * C2 + c], __float_as_int(mB));
    }
}

// ---------------------------------------------------------------------------
// Final pooled fc: relu(pooled @ fc_w + fc_b)
// ---------------------------------------------------------------------------
__global__ void poolfc_kernel(const int* __restrict__ pooledi, const float* __restrict__ fcw,
                              const float* __restrict__ fcb, float* __restrict__ outp) {
    __shared__ float mx[C2];
    int g = blockIdx.x, t = threadIdx.x;   // 128
    mx[t] = __int_as_float(pooledi[g * C2 + t]);
    __syncthreads();
    float acc = 0.f;
    for (int k = 0; k < C2; k++) acc += mx[k] * fcw[k * C2 + t];
    outp[g * C2 + t] = fmaxf(acc + fcb[t], 0.f);
}

// ---------------------------------------------------------------------------
extern "C" void kernel_launch(void* const* d_in, const int* in_sizes, int n_in,
                              void* d_out, int out_size, void* d_ws, size_t ws_size,
                              hipStream_t stream) {
    const float* feats = (const float*)d_in[0];
    const int*   ei    = (const int*)d_in[1];
    const float* W1  = (const float*)d_in[4];
    const float* a1s = (const float*)d_in[5];
    const float* a1d = (const float*)d_in[6];
    const float* b1  = (const float*)d_in[7];
    const float* W2  = (const float*)d_in[8];
    const float* a2s = (const float*)d_in[9];
    const float* a2d = (const float*)d_in[10];
    const float* b2  = (const float*)d_in[11];
    const float* fcw = (const float*)d_in[12];
    const float* fcb = (const float*)d_in[13];

    float* out_main = (float*)d_out;                        // [20000,128]
    float* out_pool = (float*)d_out + (size_t)N_NODES * C2; // [100,128]

    char* p = (char*)d_ws;
    auto alloc = [&](size_t bytes) {
        char* r = p;
        p += (bytes + 255) & ~(size_t)255;
        return r;
    };
    unsigned short* W2p  = (unsigned short*)alloc(sizeof(short) * C1 * C2);
    unsigned short* W1p  = (unsigned short*)alloc(sizeof(short) * HEADS * F_IN * F_IN);
    f16*   FCp     = (f16*)alloc(sizeof(f16) * C2 * C2);
    f16*   feats16 = (f16*)alloc(sizeof(f16) * (size_t)N_NODES * F_IN);
    f16*   xw2h    = (f16*)alloc(sizeof(f16) * (size_t)N_NODES * C2);
    float* WAs    = (float*)alloc(sizeof(float) * C1);
    float* WAd    = (float*)alloc(sizeof(float) * C1);
    float* s1s    = (float*)alloc(sizeof(float) * N_NODES * HEADS);
    float* s1d    = (float*)alloc(sizeof(float) * N_NODES * HEADS);
    float* s2s    = (float*)alloc(sizeof(float) * N_NODES);
    float* s2d    = (float*)alloc(sizeof(float) * N_NODES);
    int* cursor   = (int*)alloc(sizeof(int) * N_NODES);       // per-dst fill count
    int* pooledi  = (int*)alloc(sizeof(int) * NB * C2);       // pooled max (f32 bits)
    int* csr_src  = (int*)alloc(sizeof(int) * N_NODES * CAP); // bucket CSR

    prep_kernel<<<CURZ_BLOCKS + PLZ_BLOCKS + W2P_BLOCKS + W1P_BLOCKS + FCP_BLOCKS + F16_BLOCKS + 1,
                  256, 0, stream>>>(
        cursor, pooledi, W2, W2p, W1, W1p, fcw, FCp, a1s, a1d, WAs, WAd, feats, feats16);
    scatter_score_kernel<<<SCAT_BLOCKS + (N_NODES + 63) / 64, 256, 0, stream>>>(
        ei, cursor, csr_src, feats, WAs, WAd, s1s, s1d);

    aggh1g2_kernel<<<1250, 512, 0, stream>>>(feats16, s1s, s1d, cursor, csr_src,
                                             W1p, b1, W2p, a2s, a2d, xw2h, s2s, s2d);
    agg2fc_kernel<<<1250, 512, 0, stream>>>(xw2h, s2s, s2d, cursor, csr_src, b2,
                                            FCp, fcb, out_main, pooledi);
    poolfc_kernel<<<NB, C2, 0, stream>>>(pooledi, fcw, fcb, out_pool);
}